// Round 3
// baseline (1921.544 us; speedup 1.0000x reference)
//
#include <hip/hip_runtime.h>

#define N_NODES 100000
#define N_EDGES 1600000
#define F_IN 128
#define HID 64
#define NLAYERS 4
#define N_GRAPHS 512
#define N_CLASSES 10
#define N_TILES ((N_NODES + 255) / 256)   // 391

typedef unsigned int uint_t;

// ---------------- CSR build ----------------
__global__ __launch_bounds__(256) void k_degree(const int* __restrict__ dst, int* __restrict__ deg) {
    int i = blockIdx.x * 256 + threadIdx.x;
    if (i < N_EDGES) {
        int d = dst[i];
        if ((uint_t)d < (uint_t)N_NODES) atomicAdd(&deg[d], 1);
    }
}

__global__ __launch_bounds__(256) void k_tilesum(const int* __restrict__ deg, int* __restrict__ bsum) {
    __shared__ int sh[256];
    int tid = threadIdx.x;
    int i = blockIdx.x * 256 + tid;
    sh[tid] = (i < N_NODES) ? deg[i] : 0;
    __syncthreads();
    for (int off = 128; off > 0; off >>= 1) {
        if (tid < off) sh[tid] += sh[tid + off];
        __syncthreads();
    }
    if (tid == 0) bsum[blockIdx.x] = sh[0];
}

__global__ __launch_bounds__(512) void k_tilescan(const int* __restrict__ bsum, int* __restrict__ boff) {
    __shared__ int sh[512];
    int tid = threadIdx.x;
    sh[tid] = (tid < N_TILES) ? bsum[tid] : 0;
    __syncthreads();
    for (int off = 1; off < 512; off <<= 1) {
        int t = (tid >= off) ? sh[tid - off] : 0;
        __syncthreads();
        sh[tid] += t;
        __syncthreads();
    }
    if (tid < N_TILES) boff[tid + 1] = sh[tid];
    if (tid == 0) boff[0] = 0;
}

__global__ __launch_bounds__(256) void k_tileapply(const int* __restrict__ deg, const int* __restrict__ boff,
                                                   int* __restrict__ row_ptr) {
    __shared__ int sh[256];
    int tid = threadIdx.x, b = blockIdx.x;
    int i = b * 256 + tid;
    sh[tid] = (i < N_NODES) ? deg[i] : 0;
    __syncthreads();
    for (int off = 1; off < 256; off <<= 1) {
        int t = (tid >= off) ? sh[tid - off] : 0;
        __syncthreads();
        sh[tid] += t;
        __syncthreads();
    }
    if (i < N_NODES) row_ptr[i + 1] = boff[b] + sh[tid];
    if (i == 0) row_ptr[0] = 0;
}

__global__ __launch_bounds__(256) void k_fill(const int* __restrict__ src, const int* __restrict__ dst,
                                              int* __restrict__ cursor, int* __restrict__ col_src) {
    int i = blockIdx.x * 256 + threadIdx.x;
    if (i < N_EDGES) {
        int d = dst[i];
        if ((uint_t)d >= (uint_t)N_NODES) return;
        int pos = atomicAdd(&cursor[d], 1);
        if ((uint_t)pos < (uint_t)N_EDGES) {
            int s = src[i];
            if ((uint_t)s >= (uint_t)N_NODES) s = 0;
            col_src[pos] = s;
        }
    }
}

// ---------------- aggregation: t = (1+eps)*h + sum_{in edges} h[src]  (all f32) ----------------
template <int D>
__global__ __launch_bounds__(256) void k_aggregate(const float* __restrict__ h,
                                                   const int* __restrict__ row_ptr,
                                                   const int* __restrict__ col_src,
                                                   const float* __restrict__ eps, int layer,
                                                   float* __restrict__ t) {
    int wid = threadIdx.x >> 6, lane = threadIdx.x & 63;
    int node = blockIdx.x * 4 + wid;
    if (node >= N_NODES) return;
    float one_eps = 1.0f + eps[layer];
    int e0 = row_ptr[node], e1 = row_ptr[node + 1];
    if (e0 < 0) e0 = 0;
    if (e1 > N_EDGES) e1 = N_EDGES;
    if (e1 < e0) e1 = e0;
    if (D == 128) {
        const float2* h2 = (const float2*)h;
        float2 sw = h2[(size_t)node * 64 + lane];
        float acc0 = one_eps * sw.x;
        float acc1 = one_eps * sw.y;
        for (int e = e0; e < e1; ++e) {
            int s = col_src[e];
            if ((uint_t)s >= (uint_t)N_NODES) s = 0;
            float2 w = h2[(size_t)s * 64 + lane];
            acc0 += w.x;
            acc1 += w.y;
        }
        ((float2*)t)[(size_t)node * 64 + lane] = make_float2(acc0, acc1);
    } else {
        float acc = one_eps * h[(size_t)node * 64 + lane];
        for (int e = e0; e < e1; ++e) {
            int s = col_src[e];
            if ((uint_t)s >= (uint_t)N_NODES) s = 0;
            acc += h[(size_t)s * 64 + lane];
        }
        t[(size_t)node * 64 + lane] = acc;
    }
}

// ---------------- f32 GEMM: out[N x 64] = A[N x K] @ W[K x 64] + bias ----------------
// One wave per node-row (A reads are wave-uniform -> scalar loads); W staged in LDS.
template <int K, bool RELU>
__global__ __launch_bounds__(256) void k_gemm_f32(const float* __restrict__ A,
                                                  const float* __restrict__ W,
                                                  const float* __restrict__ bias,
                                                  float* __restrict__ out) {
    __shared__ float Wl[K * 64];
    int tid = threadIdx.x;
    for (int i = tid; i < K * 64; i += 256) Wl[i] = W[i];
    __syncthreads();
    int col = tid & 63, wv = tid >> 6;
    float b = bias[col];
    int base = blockIdx.x * 16;
    #pragma unroll
    for (int i = 0; i < 4; ++i) {
        int node = base + wv * 4 + i;
        if (node < N_NODES) {
            const float* Ar = A + (size_t)node * K;
            float acc = b;
            #pragma unroll 16
            for (int k = 0; k < K; ++k) acc += Ar[k] * Wl[k * 64 + col];
            if (RELU) acc = fmaxf(acc, 0.f);
            out[(size_t)node * 64 + col] = acc;
        }
    }
}

// ---------------- column stats over u [N_NODES x 64] ----------------
__global__ __launch_bounds__(256) void k_stats(const float* __restrict__ u, float* __restrict__ sums) {
    __shared__ float s1[256], s2[256];
    int tid = threadIdx.x;
    float a = 0.f, b = 0.f;
    for (size_t i = (size_t)blockIdx.x * 256 + tid; i < (size_t)N_NODES * 64; i += (size_t)gridDim.x * 256) {
        float v = u[i];
        a += v;
        b += v * v;
    }
    s1[tid] = a; s2[tid] = b;
    __syncthreads();
    if (tid < 128) { s1[tid] += s1[tid + 128]; s2[tid] += s2[tid + 128]; }
    __syncthreads();
    if (tid < 64) {
        atomicAdd(&sums[tid], s1[tid] + s1[tid + 64]);
        atomicAdd(&sums[64 + tid], s2[tid] + s2[tid + 64]);
    }
}

__global__ __launch_bounds__(64) void k_finalize(const float* __restrict__ sums,
                                                 const float* __restrict__ g,
                                                 const float* __restrict__ be,
                                                 float* __restrict__ scsh, float inv_n) {
    int c = threadIdx.x;
    float mean = sums[c] * inv_n;
    float var = sums[64 + c] * inv_n - mean * mean;
    if (var < 0.f) var = 0.f;
    float inv = rsqrtf(var + 1e-5f);
    float sc = inv * g[c];
    scsh[c] = sc;
    scsh[64 + c] = be[c] - mean * sc;
}

__global__ __launch_bounds__(256) void k_bnrelu(const float* __restrict__ u,
                                                const float* __restrict__ scsh,
                                                float* __restrict__ v) {
    size_t i = (size_t)blockIdx.x * 256 + threadIdx.x;
    if (i < (size_t)N_NODES * 64) {
        int c = threadIdx.x & 63;
        float x = u[i] * scsh[c] + scsh[64 + c];
        v[i] = fmaxf(x, 0.f);
    }
}

// ---------------- per-layer pooling (batch is sorted) ----------------
__global__ __launch_bounds__(64) void k_pool1(const int* __restrict__ batch,
                                              const float* __restrict__ h,
                                              float* __restrict__ pooled, int layer) {
    int g = blockIdx.x, c = threadIdx.x;
    int lo = 0, hi = N_NODES;
    while (lo < hi) { int mid = (lo + hi) >> 1; if (batch[mid] < g) lo = mid + 1; else hi = mid; }
    int s = lo;
    lo = s; hi = N_NODES;
    while (lo < hi) { int mid = (lo + hi) >> 1; if (batch[mid] < g + 1) lo = mid + 1; else hi = mid; }
    int e = lo;
    float acc = 0.f;
    for (int n = s; n < e; ++n) acc += h[(size_t)n * 64 + c];
    pooled[g * 256 + layer * 64 + c] = acc;
}

// ---------------- head ----------------
__global__ __launch_bounds__(64) void k_head1(const float* __restrict__ pooled,
                                              const float* __restrict__ W, const float* __restrict__ b,
                                              float* __restrict__ t1) {
    int g = blockIdx.x, lane = threadIdx.x;
    const float* p = pooled + g * 256;
    float acc = b[lane];
    for (int k = 0; k < 256; ++k) acc += p[k] * W[k * 64 + lane];
    t1[g * 64 + lane] = acc;
}

__global__ __launch_bounds__(64) void k_head2(const float* __restrict__ t1,
                                              const float* __restrict__ g_, const float* __restrict__ b_,
                                              float* __restrict__ scsh) {
    int c = threadIdx.x;
    float s = 0.f, q = 0.f;
    for (int r = 0; r < N_GRAPHS; ++r) {
        float v = t1[r * 64 + c];
        s += v; q += v * v;
    }
    float mean = s * (1.0f / N_GRAPHS);
    float var = q * (1.0f / N_GRAPHS) - mean * mean;
    if (var < 0.f) var = 0.f;
    float inv = rsqrtf(var + 1e-5f);
    float sc = inv * g_[c];
    scsh[c] = sc;
    scsh[64 + c] = b_[c] - mean * sc;
}

__global__ __launch_bounds__(64) void k_head3(const float* __restrict__ t1, const float* __restrict__ scsh,
                                              const float* __restrict__ W2, const float* __restrict__ b2,
                                              float* __restrict__ out) {
    __shared__ float v[64];
    __shared__ float o[16];
    int g = blockIdx.x, lane = threadIdx.x;
    float x = t1[g * 64 + lane] * scsh[lane] + scsh[64 + lane];
    v[lane] = fmaxf(x, 0.f);
    __syncthreads();
    if (lane < N_CLASSES) {
        float acc = b2[lane];
        for (int k = 0; k < 64; ++k) acc += v[k] * W2[k * N_CLASSES + lane];
        o[lane] = acc;
    }
    __syncthreads();
    if (lane < N_CLASSES) {
        float m = -1e30f;
        for (int k = 0; k < N_CLASSES; ++k) m = fmaxf(m, o[k]);
        float ssum = 0.f;
        for (int k = 0; k < N_CLASSES; ++k) ssum += expf(o[k] - m);
        out[g * N_CLASSES + lane] = o[lane] - m - logf(ssum);
    }
}

// ---------------- launch ----------------
extern "C" void kernel_launch(void* const* d_in, const int* in_sizes, int n_in,
                              void* d_out, int out_size, void* d_ws, size_t ws_size,
                              hipStream_t stream) {
    const float* x      = (const float*)d_in[0];
    const int*   ei     = (const int*)d_in[1];
    const int*   srcArr = ei;
    const int*   dstArr = ei + N_EDGES;
    const int*   batch  = (const int*)d_in[2];
    const float* eps    = (const float*)d_in[3];
    const float* W1_0   = (const float*)d_in[4];
    const float* b1_0   = (const float*)d_in[5];
    const float* g_0    = (const float*)d_in[6];
    const float* be_0   = (const float*)d_in[7];
    const float* W2_0   = (const float*)d_in[8];
    const float* b2_0   = (const float*)d_in[9];
    const float* W1_r   = (const float*)d_in[10];
    const float* b1_r   = (const float*)d_in[11];
    const float* g_r    = (const float*)d_in[12];
    const float* be_r   = (const float*)d_in[13];
    const float* W2_r   = (const float*)d_in[14];
    const float* b2_r   = (const float*)d_in[15];
    const float* lin1W  = (const float*)d_in[16];
    const float* lin1b  = (const float*)d_in[17];
    const float* bn_g   = (const float*)d_in[18];
    const float* bn_b   = (const float*)d_in[19];
    const float* lin2W  = (const float*)d_in[20];
    const float* lin2b  = (const float*)d_in[21];

    char* ws = (char*)d_ws;
    auto alloc = [&](size_t bytes) {
        char* p = ws;
        ws += (bytes + 255) & ~(size_t)255;
        return p;
    };
    int*   deg     = (int*)alloc((size_t)N_NODES * 4);
    int*   row_ptr = (int*)alloc(((size_t)N_NODES + 1) * 4);
    int*   cursor  = (int*)alloc(((size_t)N_NODES + 1) * 4);
    int*   bsum    = (int*)alloc((size_t)N_TILES * 4);
    int*   boff    = (int*)alloc(((size_t)N_TILES + 1) * 4);
    int*   col_src = (int*)alloc((size_t)N_EDGES * 4);
    float* tbuf    = (float*)alloc((size_t)N_NODES * 128 * 4);   // agg out (<=128 cols); first half reused as v
    float* u       = (float*)alloc((size_t)N_NODES * 64 * 4);
    float* hA      = (float*)alloc((size_t)N_NODES * 64 * 4);
    float* hB      = (float*)alloc((size_t)N_NODES * 64 * 4);
    float* statsA  = (float*)alloc(NLAYERS * 128 * 4);
    float* scsh    = (float*)alloc(NLAYERS * 128 * 4);
    float* pooled  = (float*)alloc((size_t)N_GRAPHS * 256 * 4);
    float* t1      = (float*)alloc((size_t)N_GRAPHS * 64 * 4);
    float* hscsh   = (float*)alloc(128 * 4);
    float* vbuf    = tbuf;   // alias: tbuf fully consumed by gemm1 before k_bnrelu writes v

    hipMemsetAsync(deg, 0, (size_t)N_NODES * 4, stream);
    hipMemsetAsync(col_src, 0, (size_t)N_EDGES * 4, stream);
    hipMemsetAsync(statsA, 0, NLAYERS * 128 * 4, stream);

    k_degree<<<(N_EDGES + 255) / 256, 256, 0, stream>>>(dstArr, deg);
    k_tilesum<<<N_TILES, 256, 0, stream>>>(deg, bsum);
    k_tilescan<<<1, 512, 0, stream>>>(bsum, boff);
    k_tileapply<<<N_TILES, 256, 0, stream>>>(deg, boff, row_ptr);
    hipMemcpyAsync(cursor, row_ptr, (size_t)N_NODES * 4, hipMemcpyDeviceToDevice, stream);
    k_fill<<<(N_EDGES + 255) / 256, 256, 0, stream>>>(srcArr, dstArr, cursor, col_src);

    const int agg_grid  = (N_NODES + 3) / 4;
    const int gemm_grid = (N_NODES + 15) / 16;
    const int ew_grid   = (N_NODES * 64 + 255) / 256;

    const float* hin = x;
    float* hping[2] = {hA, hB};
    for (int l = 0; l < NLAYERS; ++l) {
        const float *W1, *b1, *gg, *be, *W2, *b2;
        if (l == 0) { W1 = W1_0; b1 = b1_0; gg = g_0; be = be_0; W2 = W2_0; b2 = b2_0; }
        else {
            W1 = W1_r + (size_t)(l - 1) * 64 * 64;
            b1 = b1_r + (size_t)(l - 1) * 64;
            gg = g_r  + (size_t)(l - 1) * 64;
            be = be_r + (size_t)(l - 1) * 64;
            W2 = W2_r + (size_t)(l - 1) * 64 * 64;
            b2 = b2_r + (size_t)(l - 1) * 64;
        }
        float* hout = hping[l & 1];
        if (l == 0) {
            k_aggregate<128><<<agg_grid, 256, 0, stream>>>(hin, row_ptr, col_src, eps, l, tbuf);
            k_gemm_f32<128, false><<<gemm_grid, 256, 0, stream>>>(tbuf, W1, b1, u);
        } else {
            k_aggregate<64><<<agg_grid, 256, 0, stream>>>(hin, row_ptr, col_src, eps, l, tbuf);
            k_gemm_f32<64, false><<<gemm_grid, 256, 0, stream>>>(tbuf, W1, b1, u);
        }
        k_stats<<<256, 256, 0, stream>>>(u, statsA + l * 128);
        k_finalize<<<1, 64, 0, stream>>>(statsA + l * 128, gg, be, scsh + l * 128, 1.0f / N_NODES);
        k_bnrelu<<<ew_grid, 256, 0, stream>>>(u, scsh + l * 128, vbuf);
        k_gemm_f32<64, true><<<gemm_grid, 256, 0, stream>>>(vbuf, W2, b2, hout);
        k_pool1<<<N_GRAPHS, 64, 0, stream>>>(batch, hout, pooled, l);
        hin = hout;
    }

    k_head1<<<N_GRAPHS, 64, 0, stream>>>(pooled, lin1W, lin1b, t1);
    k_head2<<<1, 64, 0, stream>>>(t1, bn_g, bn_b, hscsh);
    k_head3<<<N_GRAPHS, 64, 0, stream>>>(t1, hscsh, lin2W, lin2b, (float*)d_out);
}

// Round 4
// 1386.864 us; speedup vs baseline: 1.3855x; 1.3855x over previous
//
#include <hip/hip_runtime.h>

#define N_NODES 100000
#define N_EDGES 1600000
#define F_IN 128
#define HID 64
#define NLAYERS 4
#define N_GRAPHS 512
#define N_CLASSES 10
#define N_TILES ((N_NODES + 255) / 256)   // 391

typedef unsigned int uint_t;

// ---------------- CSR build ----------------
__global__ __launch_bounds__(256) void k_degree(const int* __restrict__ dst, int* __restrict__ deg) {
    int i = blockIdx.x * 256 + threadIdx.x;
    if (i < N_EDGES) {
        int d = dst[i];
        if ((uint_t)d < (uint_t)N_NODES) atomicAdd(&deg[d], 1);
    }
}

__global__ __launch_bounds__(256) void k_tilesum(const int* __restrict__ deg, int* __restrict__ bsum) {
    __shared__ int sh[256];
    int tid = threadIdx.x;
    int i = blockIdx.x * 256 + tid;
    sh[tid] = (i < N_NODES) ? deg[i] : 0;
    __syncthreads();
    for (int off = 128; off > 0; off >>= 1) {
        if (tid < off) sh[tid] += sh[tid + off];
        __syncthreads();
    }
    if (tid == 0) bsum[blockIdx.x] = sh[0];
}

__global__ __launch_bounds__(512) void k_tilescan(const int* __restrict__ bsum, int* __restrict__ boff) {
    __shared__ int sh[512];
    int tid = threadIdx.x;
    sh[tid] = (tid < N_TILES) ? bsum[tid] : 0;
    __syncthreads();
    for (int off = 1; off < 512; off <<= 1) {
        int t = (tid >= off) ? sh[tid - off] : 0;
        __syncthreads();
        sh[tid] += t;
        __syncthreads();
    }
    if (tid < N_TILES) boff[tid + 1] = sh[tid];
    if (tid == 0) boff[0] = 0;
}

__global__ __launch_bounds__(256) void k_tileapply(const int* __restrict__ deg, const int* __restrict__ boff,
                                                   int* __restrict__ row_ptr) {
    __shared__ int sh[256];
    int tid = threadIdx.x, b = blockIdx.x;
    int i = b * 256 + tid;
    sh[tid] = (i < N_NODES) ? deg[i] : 0;
    __syncthreads();
    for (int off = 1; off < 256; off <<= 1) {
        int t = (tid >= off) ? sh[tid - off] : 0;
        __syncthreads();
        sh[tid] += t;
        __syncthreads();
    }
    if (i < N_NODES) row_ptr[i + 1] = boff[b] + sh[tid];
    if (i == 0) row_ptr[0] = 0;
}

__global__ __launch_bounds__(256) void k_fill(const int* __restrict__ src, const int* __restrict__ dst,
                                              int* __restrict__ cursor, int* __restrict__ col_src) {
    int i = blockIdx.x * 256 + threadIdx.x;
    if (i < N_EDGES) {
        int d = dst[i];
        if ((uint_t)d >= (uint_t)N_NODES) return;
        int pos = atomicAdd(&cursor[d], 1);
        if ((uint_t)pos < (uint_t)N_EDGES) {
            int s = src[i];
            if ((uint_t)s >= (uint_t)N_NODES) s = 0;
            col_src[pos] = s;
        }
    }
}

// ---------------- aggregation: t = (1+eps)*h + sum_{in edges} h[src]  (all f32) ----------------
// Latency-bound -> 8 independent gather streams per wave.
template <int D>
__global__ __launch_bounds__(256) void k_aggregate(const float* __restrict__ h,
                                                   const int* __restrict__ row_ptr,
                                                   const int* __restrict__ col_src,
                                                   const float* __restrict__ eps, int layer,
                                                   float* __restrict__ t) {
    int wid = threadIdx.x >> 6, lane = threadIdx.x & 63;
    int node = blockIdx.x * 4 + wid;
    if (node >= N_NODES) return;
    float one_eps = 1.0f + eps[layer];
    int e0 = row_ptr[node], e1 = row_ptr[node + 1];
    if (e0 < 0) e0 = 0;
    if (e1 > N_EDGES) e1 = N_EDGES;
    if (e1 < e0) e1 = e0;

    if (D == 128) {
        const float2* h2 = (const float2*)h;
        float2 sw = h2[(size_t)node * 64 + lane];
        float ax0 = one_eps * sw.x, ay0 = one_eps * sw.y;
        float ax1 = 0.f, ay1 = 0.f, ax2 = 0.f, ay2 = 0.f, ax3 = 0.f, ay3 = 0.f;
        float ax4 = 0.f, ay4 = 0.f, ax5 = 0.f, ay5 = 0.f, ax6 = 0.f, ay6 = 0.f, ax7 = 0.f, ay7 = 0.f;
        int e = e0;
        for (; e + 8 <= e1; e += 8) {
            int s0 = col_src[e + 0], s1 = col_src[e + 1], s2 = col_src[e + 2], s3 = col_src[e + 3];
            int s4 = col_src[e + 4], s5 = col_src[e + 5], s6 = col_src[e + 6], s7 = col_src[e + 7];
            if ((uint_t)s0 >= (uint_t)N_NODES) s0 = 0;
            if ((uint_t)s1 >= (uint_t)N_NODES) s1 = 0;
            if ((uint_t)s2 >= (uint_t)N_NODES) s2 = 0;
            if ((uint_t)s3 >= (uint_t)N_NODES) s3 = 0;
            if ((uint_t)s4 >= (uint_t)N_NODES) s4 = 0;
            if ((uint_t)s5 >= (uint_t)N_NODES) s5 = 0;
            if ((uint_t)s6 >= (uint_t)N_NODES) s6 = 0;
            if ((uint_t)s7 >= (uint_t)N_NODES) s7 = 0;
            float2 v0 = h2[(size_t)s0 * 64 + lane];
            float2 v1 = h2[(size_t)s1 * 64 + lane];
            float2 v2 = h2[(size_t)s2 * 64 + lane];
            float2 v3 = h2[(size_t)s3 * 64 + lane];
            float2 v4 = h2[(size_t)s4 * 64 + lane];
            float2 v5 = h2[(size_t)s5 * 64 + lane];
            float2 v6 = h2[(size_t)s6 * 64 + lane];
            float2 v7 = h2[(size_t)s7 * 64 + lane];
            ax0 += v0.x; ay0 += v0.y;
            ax1 += v1.x; ay1 += v1.y;
            ax2 += v2.x; ay2 += v2.y;
            ax3 += v3.x; ay3 += v3.y;
            ax4 += v4.x; ay4 += v4.y;
            ax5 += v5.x; ay5 += v5.y;
            ax6 += v6.x; ay6 += v6.y;
            ax7 += v7.x; ay7 += v7.y;
        }
        for (; e < e1; ++e) {
            int s = col_src[e];
            if ((uint_t)s >= (uint_t)N_NODES) s = 0;
            float2 w = h2[(size_t)s * 64 + lane];
            ax0 += w.x; ay0 += w.y;
        }
        float ox = ((ax0 + ax1) + (ax2 + ax3)) + ((ax4 + ax5) + (ax6 + ax7));
        float oy = ((ay0 + ay1) + (ay2 + ay3)) + ((ay4 + ay5) + (ay6 + ay7));
        ((float2*)t)[(size_t)node * 64 + lane] = make_float2(ox, oy);
    } else {
        float a0 = one_eps * h[(size_t)node * 64 + lane];
        float a1 = 0.f, a2 = 0.f, a3 = 0.f, a4 = 0.f, a5 = 0.f, a6 = 0.f, a7 = 0.f;
        int e = e0;
        for (; e + 8 <= e1; e += 8) {
            int s0 = col_src[e + 0], s1 = col_src[e + 1], s2 = col_src[e + 2], s3 = col_src[e + 3];
            int s4 = col_src[e + 4], s5 = col_src[e + 5], s6 = col_src[e + 6], s7 = col_src[e + 7];
            if ((uint_t)s0 >= (uint_t)N_NODES) s0 = 0;
            if ((uint_t)s1 >= (uint_t)N_NODES) s1 = 0;
            if ((uint_t)s2 >= (uint_t)N_NODES) s2 = 0;
            if ((uint_t)s3 >= (uint_t)N_NODES) s3 = 0;
            if ((uint_t)s4 >= (uint_t)N_NODES) s4 = 0;
            if ((uint_t)s5 >= (uint_t)N_NODES) s5 = 0;
            if ((uint_t)s6 >= (uint_t)N_NODES) s6 = 0;
            if ((uint_t)s7 >= (uint_t)N_NODES) s7 = 0;
            float v0 = h[(size_t)s0 * 64 + lane];
            float v1 = h[(size_t)s1 * 64 + lane];
            float v2 = h[(size_t)s2 * 64 + lane];
            float v3 = h[(size_t)s3 * 64 + lane];
            float v4 = h[(size_t)s4 * 64 + lane];
            float v5 = h[(size_t)s5 * 64 + lane];
            float v6 = h[(size_t)s6 * 64 + lane];
            float v7 = h[(size_t)s7 * 64 + lane];
            a0 += v0; a1 += v1; a2 += v2; a3 += v3;
            a4 += v4; a5 += v5; a6 += v6; a7 += v7;
        }
        for (; e < e1; ++e) {
            int s = col_src[e];
            if ((uint_t)s >= (uint_t)N_NODES) s = 0;
            a0 += h[(size_t)s * 64 + lane];
        }
        t[(size_t)node * 64 + lane] = ((a0 + a1) + (a2 + a3)) + ((a4 + a5) + (a6 + a7));
    }
}

// ---------------- f32 GEMM: out[N x 64] = A[N x K] @ W[K x 64] + bias ----------------
// k-outer: one LDS read of W serves 4 row-FMAs; 4 independent A-row scalar streams.
// N_NODES % 16 == 0 so no row bounds checks.
template <int K, bool RELU>
__global__ __launch_bounds__(256) void k_gemm_f32(const float* __restrict__ A,
                                                  const float* __restrict__ W,
                                                  const float* __restrict__ bias,
                                                  float* __restrict__ out) {
    __shared__ float Wl[K * 64];
    int tid = threadIdx.x;
    for (int i = tid; i < K * 64; i += 256) Wl[i] = W[i];
    __syncthreads();
    int col = tid & 63, wv = tid >> 6;
    float b = bias[col];
    int base = blockIdx.x * 16 + wv * 4;
    const float* A0 = A + (size_t)base * K;
    const float* A1 = A0 + K;
    const float* A2 = A1 + K;
    const float* A3 = A2 + K;
    float acc0 = b, acc1 = b, acc2 = b, acc3 = b;
    #pragma unroll 8
    for (int k = 0; k < K; ++k) {
        float wk = Wl[k * 64 + col];
        acc0 += A0[k] * wk;
        acc1 += A1[k] * wk;
        acc2 += A2[k] * wk;
        acc3 += A3[k] * wk;
    }
    if (RELU) {
        acc0 = fmaxf(acc0, 0.f); acc1 = fmaxf(acc1, 0.f);
        acc2 = fmaxf(acc2, 0.f); acc3 = fmaxf(acc3, 0.f);
    }
    out[(size_t)(base + 0) * 64 + col] = acc0;
    out[(size_t)(base + 1) * 64 + col] = acc1;
    out[(size_t)(base + 2) * 64 + col] = acc2;
    out[(size_t)(base + 3) * 64 + col] = acc3;
}

// ---------------- column stats over u [N_NODES x 64] ----------------
__global__ __launch_bounds__(256) void k_stats(const float* __restrict__ u, float* __restrict__ sums) {
    __shared__ float s1[256], s2[256];
    int tid = threadIdx.x;
    float a = 0.f, b = 0.f;
    for (size_t i = (size_t)blockIdx.x * 256 + tid; i < (size_t)N_NODES * 64; i += (size_t)gridDim.x * 256) {
        float v = u[i];
        a += v;
        b += v * v;
    }
    s1[tid] = a; s2[tid] = b;
    __syncthreads();
    if (tid < 128) { s1[tid] += s1[tid + 128]; s2[tid] += s2[tid + 128]; }
    __syncthreads();
    if (tid < 64) {
        atomicAdd(&sums[tid], s1[tid] + s1[tid + 64]);
        atomicAdd(&sums[64 + tid], s2[tid] + s2[tid + 64]);
    }
}

__global__ __launch_bounds__(64) void k_finalize(const float* __restrict__ sums,
                                                 const float* __restrict__ g,
                                                 const float* __restrict__ be,
                                                 float* __restrict__ scsh, float inv_n) {
    int c = threadIdx.x;
    float mean = sums[c] * inv_n;
    float var = sums[64 + c] * inv_n - mean * mean;
    if (var < 0.f) var = 0.f;
    float inv = rsqrtf(var + 1e-5f);
    float sc = inv * g[c];
    scsh[c] = sc;
    scsh[64 + c] = be[c] - mean * sc;
}

// float4 over N_NODES*16 vectors (exactly divisible by 256)
__global__ __launch_bounds__(256) void k_bnrelu(const float4* __restrict__ u4,
                                                const float* __restrict__ scsh,
                                                float4* __restrict__ v4) {
    size_t i = (size_t)blockIdx.x * 256 + threadIdx.x;
    int c4 = (threadIdx.x & 15) * 4;
    float4 x = u4[i];
    x.x = fmaxf(x.x * scsh[c4 + 0] + scsh[64 + c4 + 0], 0.f);
    x.y = fmaxf(x.y * scsh[c4 + 1] + scsh[64 + c4 + 1], 0.f);
    x.z = fmaxf(x.z * scsh[c4 + 2] + scsh[64 + c4 + 2], 0.f);
    x.w = fmaxf(x.w * scsh[c4 + 3] + scsh[64 + c4 + 3], 0.f);
    v4[i] = x;
}

// ---------------- per-layer pooling (batch is sorted) ----------------
__global__ __launch_bounds__(64) void k_pool1(const int* __restrict__ batch,
                                              const float* __restrict__ h,
                                              float* __restrict__ pooled, int layer) {
    int g = blockIdx.x, c = threadIdx.x;
    int lo = 0, hi = N_NODES;
    while (lo < hi) { int mid = (lo + hi) >> 1; if (batch[mid] < g) lo = mid + 1; else hi = mid; }
    int s = lo;
    lo = s; hi = N_NODES;
    while (lo < hi) { int mid = (lo + hi) >> 1; if (batch[mid] < g + 1) lo = mid + 1; else hi = mid; }
    int e = lo;
    float a0 = 0.f, a1 = 0.f, a2 = 0.f, a3 = 0.f, a4 = 0.f, a5 = 0.f, a6 = 0.f, a7 = 0.f;
    int n = s;
    for (; n + 8 <= e; n += 8) {
        a0 += h[(size_t)(n + 0) * 64 + c];
        a1 += h[(size_t)(n + 1) * 64 + c];
        a2 += h[(size_t)(n + 2) * 64 + c];
        a3 += h[(size_t)(n + 3) * 64 + c];
        a4 += h[(size_t)(n + 4) * 64 + c];
        a5 += h[(size_t)(n + 5) * 64 + c];
        a6 += h[(size_t)(n + 6) * 64 + c];
        a7 += h[(size_t)(n + 7) * 64 + c];
    }
    for (; n < e; ++n) a0 += h[(size_t)n * 64 + c];
    pooled[g * 256 + layer * 64 + c] = ((a0 + a1) + (a2 + a3)) + ((a4 + a5) + (a6 + a7));
}

// ---------------- head ----------------
__global__ __launch_bounds__(64) void k_head1(const float* __restrict__ pooled,
                                              const float* __restrict__ W, const float* __restrict__ b,
                                              float* __restrict__ t1) {
    int g = blockIdx.x, lane = threadIdx.x;
    const float* p = pooled + g * 256;
    float acc = b[lane];
    for (int k = 0; k < 256; ++k) acc += p[k] * W[k * 64 + lane];
    t1[g * 64 + lane] = acc;
}

__global__ __launch_bounds__(64) void k_head2(const float* __restrict__ t1,
                                              const float* __restrict__ g_, const float* __restrict__ b_,
                                              float* __restrict__ scsh) {
    int c = threadIdx.x;
    float s = 0.f, q = 0.f;
    for (int r = 0; r < N_GRAPHS; ++r) {
        float v = t1[r * 64 + c];
        s += v; q += v * v;
    }
    float mean = s * (1.0f / N_GRAPHS);
    float var = q * (1.0f / N_GRAPHS) - mean * mean;
    if (var < 0.f) var = 0.f;
    float inv = rsqrtf(var + 1e-5f);
    float sc = inv * g_[c];
    scsh[c] = sc;
    scsh[64 + c] = b_[c] - mean * sc;
}

__global__ __launch_bounds__(64) void k_head3(const float* __restrict__ t1, const float* __restrict__ scsh,
                                              const float* __restrict__ W2, const float* __restrict__ b2,
                                              float* __restrict__ out) {
    __shared__ float v[64];
    __shared__ float o[16];
    int g = blockIdx.x, lane = threadIdx.x;
    float x = t1[g * 64 + lane] * scsh[lane] + scsh[64 + lane];
    v[lane] = fmaxf(x, 0.f);
    __syncthreads();
    if (lane < N_CLASSES) {
        float acc = b2[lane];
        for (int k = 0; k < 64; ++k) acc += v[k] * W2[k * N_CLASSES + lane];
        o[lane] = acc;
    }
    __syncthreads();
    if (lane < N_CLASSES) {
        float m = -1e30f;
        for (int k = 0; k < N_CLASSES; ++k) m = fmaxf(m, o[k]);
        float ssum = 0.f;
        for (int k = 0; k < N_CLASSES; ++k) ssum += expf(o[k] - m);
        out[g * N_CLASSES + lane] = o[lane] - m - logf(ssum);
    }
}

// ---------------- launch ----------------
extern "C" void kernel_launch(void* const* d_in, const int* in_sizes, int n_in,
                              void* d_out, int out_size, void* d_ws, size_t ws_size,
                              hipStream_t stream) {
    const float* x      = (const float*)d_in[0];
    const int*   ei     = (const int*)d_in[1];
    const int*   srcArr = ei;
    const int*   dstArr = ei + N_EDGES;
    const int*   batch  = (const int*)d_in[2];
    const float* eps    = (const float*)d_in[3];
    const float* W1_0   = (const float*)d_in[4];
    const float* b1_0   = (const float*)d_in[5];
    const float* g_0    = (const float*)d_in[6];
    const float* be_0   = (const float*)d_in[7];
    const float* W2_0   = (const float*)d_in[8];
    const float* b2_0   = (const float*)d_in[9];
    const float* W1_r   = (const float*)d_in[10];
    const float* b1_r   = (const float*)d_in[11];
    const float* g_r    = (const float*)d_in[12];
    const float* be_r   = (const float*)d_in[13];
    const float* W2_r   = (const float*)d_in[14];
    const float* b2_r   = (const float*)d_in[15];
    const float* lin1W  = (const float*)d_in[16];
    const float* lin1b  = (const float*)d_in[17];
    const float* bn_g   = (const float*)d_in[18];
    const float* bn_b   = (const float*)d_in[19];
    const float* lin2W  = (const float*)d_in[20];
    const float* lin2b  = (const float*)d_in[21];

    char* ws = (char*)d_ws;
    auto alloc = [&](size_t bytes) {
        char* p = ws;
        ws += (bytes + 255) & ~(size_t)255;
        return p;
    };
    int*   deg     = (int*)alloc((size_t)N_NODES * 4);
    int*   row_ptr = (int*)alloc(((size_t)N_NODES + 1) * 4);
    int*   cursor  = (int*)alloc(((size_t)N_NODES + 1) * 4);
    int*   bsum    = (int*)alloc((size_t)N_TILES * 4);
    int*   boff    = (int*)alloc(((size_t)N_TILES + 1) * 4);
    int*   col_src = (int*)alloc((size_t)N_EDGES * 4);
    float* tbuf    = (float*)alloc((size_t)N_NODES * 128 * 4);
    float* u       = (float*)alloc((size_t)N_NODES * 64 * 4);
    float* hA      = (float*)alloc((size_t)N_NODES * 64 * 4);
    float* hB      = (float*)alloc((size_t)N_NODES * 64 * 4);
    float* statsA  = (float*)alloc(NLAYERS * 128 * 4);
    float* scsh    = (float*)alloc(NLAYERS * 128 * 4);
    float* pooled  = (float*)alloc((size_t)N_GRAPHS * 256 * 4);
    float* t1      = (float*)alloc((size_t)N_GRAPHS * 64 * 4);
    float* hscsh   = (float*)alloc(128 * 4);
    float* vbuf    = tbuf;   // alias: tbuf fully consumed by gemm1 before k_bnrelu writes v

    hipMemsetAsync(deg, 0, (size_t)N_NODES * 4, stream);
    hipMemsetAsync(col_src, 0, (size_t)N_EDGES * 4, stream);
    hipMemsetAsync(statsA, 0, NLAYERS * 128 * 4, stream);

    k_degree<<<(N_EDGES + 255) / 256, 256, 0, stream>>>(dstArr, deg);
    k_tilesum<<<N_TILES, 256, 0, stream>>>(deg, bsum);
    k_tilescan<<<1, 512, 0, stream>>>(bsum, boff);
    k_tileapply<<<N_TILES, 256, 0, stream>>>(deg, boff, row_ptr);
    hipMemcpyAsync(cursor, row_ptr, (size_t)N_NODES * 4, hipMemcpyDeviceToDevice, stream);
    k_fill<<<(N_EDGES + 255) / 256, 256, 0, stream>>>(srcArr, dstArr, cursor, col_src);

    const int agg_grid  = (N_NODES + 3) / 4;
    const int gemm_grid = N_NODES / 16;           // 6250, exact
    const int ew4_grid  = N_NODES * 16 / 256;     // 6250, exact (float4)

    const float* hin = x;
    float* hping[2] = {hA, hB};
    for (int l = 0; l < NLAYERS; ++l) {
        const float *W1, *b1, *gg, *be, *W2, *b2;
        if (l == 0) { W1 = W1_0; b1 = b1_0; gg = g_0; be = be_0; W2 = W2_0; b2 = b2_0; }
        else {
            W1 = W1_r + (size_t)(l - 1) * 64 * 64;
            b1 = b1_r + (size_t)(l - 1) * 64;
            gg = g_r  + (size_t)(l - 1) * 64;
            be = be_r + (size_t)(l - 1) * 64;
            W2 = W2_r + (size_t)(l - 1) * 64 * 64;
            b2 = b2_r + (size_t)(l - 1) * 64;
        }
        float* hout = hping[l & 1];
        if (l == 0) {
            k_aggregate<128><<<agg_grid, 256, 0, stream>>>(hin, row_ptr, col_src, eps, l, tbuf);
            k_gemm_f32<128, false><<<gemm_grid, 256, 0, stream>>>(tbuf, W1, b1, u);
        } else {
            k_aggregate<64><<<agg_grid, 256, 0, stream>>>(hin, row_ptr, col_src, eps, l, tbuf);
            k_gemm_f32<64, false><<<gemm_grid, 256, 0, stream>>>(tbuf, W1, b1, u);
        }
        k_stats<<<256, 256, 0, stream>>>(u, statsA + l * 128);
        k_finalize<<<1, 64, 0, stream>>>(statsA + l * 128, gg, be, scsh + l * 128, 1.0f / N_NODES);
        k_bnrelu<<<ew4_grid, 256, 0, stream>>>((const float4*)u, scsh + l * 128, (float4*)vbuf);
        k_gemm_f32<64, true><<<gemm_grid, 256, 0, stream>>>(vbuf, W2, b2, hout);
        k_pool1<<<N_GRAPHS, 64, 0, stream>>>(batch, hout, pooled, l);
        hin = hout;
    }

    k_head1<<<N_GRAPHS, 64, 0, stream>>>(pooled, lin1W, lin1b, t1);
    k_head2<<<1, 64, 0, stream>>>(t1, bn_g, bn_b, hscsh);
    k_head3<<<N_GRAPHS, 64, 0, stream>>>(t1, hscsh, lin2W, lin2b, (float*)d_out);
}

// Round 5
// 1292.835 us; speedup vs baseline: 1.4863x; 1.0727x over previous
//
#include <hip/hip_runtime.h>

#define N_NODES 100000
#define N_EDGES 1600000
#define F_IN 128
#define HID 64
#define NLAYERS 4
#define N_GRAPHS 512
#define N_CLASSES 10
#define N_TILES ((N_NODES + 255) / 256)   // 391

typedef unsigned int uint_t;

// ---------------- CSR build ----------------
// 4 edges/thread -> 4 independent atomic streams (latency-bound fix)
__global__ __launch_bounds__(256) void k_degree(const int* __restrict__ dst, int* __restrict__ deg) {
    int base = blockIdx.x * 1024 + threadIdx.x;
    #pragma unroll
    for (int j = 0; j < 4; ++j) {
        int e = base + j * 256;
        if (e < N_EDGES) {
            int d = dst[e];
            if ((uint_t)d < (uint_t)N_NODES) atomicAdd(&deg[d], 1);
        }
    }
}

__global__ __launch_bounds__(256) void k_tilesum(const int* __restrict__ deg, int* __restrict__ bsum) {
    __shared__ int sh[256];
    int tid = threadIdx.x;
    int i = blockIdx.x * 256 + tid;
    sh[tid] = (i < N_NODES) ? deg[i] : 0;
    __syncthreads();
    for (int off = 128; off > 0; off >>= 1) {
        if (tid < off) sh[tid] += sh[tid + off];
        __syncthreads();
    }
    if (tid == 0) bsum[blockIdx.x] = sh[0];
}

__global__ __launch_bounds__(512) void k_tilescan(const int* __restrict__ bsum, int* __restrict__ boff) {
    __shared__ int sh[512];
    int tid = threadIdx.x;
    sh[tid] = (tid < N_TILES) ? bsum[tid] : 0;
    __syncthreads();
    for (int off = 1; off < 512; off <<= 1) {
        int t = (tid >= off) ? sh[tid - off] : 0;
        __syncthreads();
        sh[tid] += t;
        __syncthreads();
    }
    if (tid < N_TILES) boff[tid + 1] = sh[tid];
    if (tid == 0) boff[0] = 0;
}

__global__ __launch_bounds__(256) void k_tileapply(const int* __restrict__ deg, const int* __restrict__ boff,
                                                   int* __restrict__ row_ptr) {
    __shared__ int sh[256];
    int tid = threadIdx.x, b = blockIdx.x;
    int i = b * 256 + tid;
    sh[tid] = (i < N_NODES) ? deg[i] : 0;
    __syncthreads();
    for (int off = 1; off < 256; off <<= 1) {
        int t = (tid >= off) ? sh[tid - off] : 0;
        __syncthreads();
        sh[tid] += t;
        __syncthreads();
    }
    if (i < N_NODES) row_ptr[i + 1] = boff[b] + sh[tid];
    if (i == 0) row_ptr[0] = 0;
}

__global__ __launch_bounds__(256) void k_fill(const int* __restrict__ src, const int* __restrict__ dst,
                                              int* __restrict__ cursor, int* __restrict__ col_src) {
    int base = blockIdx.x * 1024 + threadIdx.x;
    int e0 = base, e1 = base + 256, e2 = base + 512, e3 = base + 768;
    bool v0 = e0 < N_EDGES, v1 = e1 < N_EDGES, v2 = e2 < N_EDGES, v3 = e3 < N_EDGES;
    int d0 = v0 ? dst[e0] : 0, d1 = v1 ? dst[e1] : 0, d2 = v2 ? dst[e2] : 0, d3 = v3 ? dst[e3] : 0;
    int s0 = v0 ? src[e0] : 0, s1 = v1 ? src[e1] : 0, s2 = v2 ? src[e2] : 0, s3 = v3 ? src[e3] : 0;
    v0 = v0 && (uint_t)d0 < (uint_t)N_NODES;
    v1 = v1 && (uint_t)d1 < (uint_t)N_NODES;
    v2 = v2 && (uint_t)d2 < (uint_t)N_NODES;
    v3 = v3 && (uint_t)d3 < (uint_t)N_NODES;
    int p0 = v0 ? atomicAdd(&cursor[d0], 1) : 0;
    int p1 = v1 ? atomicAdd(&cursor[d1], 1) : 0;
    int p2 = v2 ? atomicAdd(&cursor[d2], 1) : 0;
    int p3 = v3 ? atomicAdd(&cursor[d3], 1) : 0;
    if ((uint_t)s0 >= (uint_t)N_NODES) s0 = 0;
    if ((uint_t)s1 >= (uint_t)N_NODES) s1 = 0;
    if ((uint_t)s2 >= (uint_t)N_NODES) s2 = 0;
    if ((uint_t)s3 >= (uint_t)N_NODES) s3 = 0;
    if (v0 && (uint_t)p0 < (uint_t)N_EDGES) col_src[p0] = s0;
    if (v1 && (uint_t)p1 < (uint_t)N_EDGES) col_src[p1] = s1;
    if (v2 && (uint_t)p2 < (uint_t)N_EDGES) col_src[p2] = s2;
    if (v3 && (uint_t)p3 < (uint_t)N_EDGES) col_src[p3] = s3;
}

// ---------------- aggregation on post-GEMM features (dim 64 always) ----------------
// u[node] = (1+eps)*y[node] + sum_{in edges} y[src] + b1   (W1 pushed through by linearity)
__global__ __launch_bounds__(256) void k_aggregate_u(const float* __restrict__ y,
                                                     const int* __restrict__ row_ptr,
                                                     const int* __restrict__ col_src,
                                                     const float* __restrict__ eps, int layer,
                                                     const float* __restrict__ b1,
                                                     float* __restrict__ u) {
    int wid = threadIdx.x >> 6, lane = threadIdx.x & 63;
    int node = blockIdx.x * 4 + wid;
    if (node >= N_NODES) return;
    float one_eps = 1.0f + eps[layer];
    int e0 = row_ptr[node], e1 = row_ptr[node + 1];
    if (e0 < 0) e0 = 0;
    if (e1 > N_EDGES) e1 = N_EDGES;
    if (e1 < e0) e1 = e0;

    float a0 = one_eps * y[(size_t)node * 64 + lane] + b1[lane];
    float a1 = 0.f, a2 = 0.f, a3 = 0.f, a4 = 0.f, a5 = 0.f, a6 = 0.f, a7 = 0.f;
    int e = e0;
    for (; e + 8 <= e1; e += 8) {
        int s0 = col_src[e + 0], s1 = col_src[e + 1], s2 = col_src[e + 2], s3 = col_src[e + 3];
        int s4 = col_src[e + 4], s5 = col_src[e + 5], s6 = col_src[e + 6], s7 = col_src[e + 7];
        if ((uint_t)s0 >= (uint_t)N_NODES) s0 = 0;
        if ((uint_t)s1 >= (uint_t)N_NODES) s1 = 0;
        if ((uint_t)s2 >= (uint_t)N_NODES) s2 = 0;
        if ((uint_t)s3 >= (uint_t)N_NODES) s3 = 0;
        if ((uint_t)s4 >= (uint_t)N_NODES) s4 = 0;
        if ((uint_t)s5 >= (uint_t)N_NODES) s5 = 0;
        if ((uint_t)s6 >= (uint_t)N_NODES) s6 = 0;
        if ((uint_t)s7 >= (uint_t)N_NODES) s7 = 0;
        float v0 = y[(size_t)s0 * 64 + lane];
        float v1 = y[(size_t)s1 * 64 + lane];
        float v2 = y[(size_t)s2 * 64 + lane];
        float v3 = y[(size_t)s3 * 64 + lane];
        float v4 = y[(size_t)s4 * 64 + lane];
        float v5 = y[(size_t)s5 * 64 + lane];
        float v6 = y[(size_t)s6 * 64 + lane];
        float v7 = y[(size_t)s7 * 64 + lane];
        a0 += v0; a1 += v1; a2 += v2; a3 += v3;
        a4 += v4; a5 += v5; a6 += v6; a7 += v7;
    }
    for (; e < e1; ++e) {
        int s = col_src[e];
        if ((uint_t)s >= (uint_t)N_NODES) s = 0;
        a0 += y[(size_t)s * 64 + lane];
    }
    u[(size_t)node * 64 + lane] = ((a0 + a1) + (a2 + a3)) + ((a4 + a5) + (a6 + a7));
}

// ---------------- f32 GEMM: out[N x 64] = A[N x K] @ W[K x 64]  (no bias, no act) ----------------
template <int K>
__global__ __launch_bounds__(256) void k_gemm_f32(const float* __restrict__ A,
                                                  const float* __restrict__ W,
                                                  float* __restrict__ out) {
    __shared__ float Wl[K * 64];
    int tid = threadIdx.x;
    for (int i = tid; i < K * 64; i += 256) Wl[i] = W[i];
    __syncthreads();
    int col = tid & 63, wv = tid >> 6;
    int base = blockIdx.x * 16 + wv * 4;
    const float* A0 = A + (size_t)base * K;
    const float* A1 = A0 + K;
    const float* A2 = A1 + K;
    const float* A3 = A2 + K;
    float acc0 = 0.f, acc1 = 0.f, acc2 = 0.f, acc3 = 0.f;
    #pragma unroll 8
    for (int k = 0; k < K; ++k) {
        float wk = Wl[k * 64 + col];
        acc0 += A0[k] * wk;
        acc1 += A1[k] * wk;
        acc2 += A2[k] * wk;
        acc3 += A3[k] * wk;
    }
    out[(size_t)(base + 0) * 64 + col] = acc0;
    out[(size_t)(base + 1) * 64 + col] = acc1;
    out[(size_t)(base + 2) * 64 + col] = acc2;
    out[(size_t)(base + 3) * 64 + col] = acc3;
}

// ---------------- GEMM2 with BN+ReLU fused on the A-load ----------------
// out[row][col] = relu( sum_k relu(u[row][k]*sc[k]+sh[k]) * W[k][col] + b2[col] )   [outer relu]
__global__ __launch_bounds__(256) void k_gemm_bn(const float* __restrict__ U,
                                                 const float* __restrict__ W,
                                                 const float* __restrict__ scsh,
                                                 const float* __restrict__ b2,
                                                 float* __restrict__ out) {
    __shared__ float Wl[64 * 64];
    __shared__ float Sc[64], Sh[64];
    int tid = threadIdx.x;
    for (int i = tid; i < 64 * 64; i += 256) Wl[i] = W[i];
    if (tid < 64) { Sc[tid] = scsh[tid]; Sh[tid] = scsh[64 + tid]; }
    __syncthreads();
    int col = tid & 63, wv = tid >> 6;
    float b = b2[col];
    int base = blockIdx.x * 16 + wv * 4;
    const float* A0 = U + (size_t)base * 64;
    const float* A1 = A0 + 64;
    const float* A2 = A1 + 64;
    const float* A3 = A2 + 64;
    float acc0 = b, acc1 = b, acc2 = b, acc3 = b;
    #pragma unroll 8
    for (int k = 0; k < 64; ++k) {
        float wk = Wl[k * 64 + col];
        float sck = Sc[k], shk = Sh[k];
        float v0 = fmaxf(fmaf(A0[k], sck, shk), 0.f);
        float v1 = fmaxf(fmaf(A1[k], sck, shk), 0.f);
        float v2 = fmaxf(fmaf(A2[k], sck, shk), 0.f);
        float v3 = fmaxf(fmaf(A3[k], sck, shk), 0.f);
        acc0 = fmaf(v0, wk, acc0);
        acc1 = fmaf(v1, wk, acc1);
        acc2 = fmaf(v2, wk, acc2);
        acc3 = fmaf(v3, wk, acc3);
    }
    acc0 = fmaxf(acc0, 0.f); acc1 = fmaxf(acc1, 0.f);
    acc2 = fmaxf(acc2, 0.f); acc3 = fmaxf(acc3, 0.f);
    out[(size_t)(base + 0) * 64 + col] = acc0;
    out[(size_t)(base + 1) * 64 + col] = acc1;
    out[(size_t)(base + 2) * 64 + col] = acc2;
    out[(size_t)(base + 3) * 64 + col] = acc3;
}

// ---------------- column stats over u [N_NODES x 64] ----------------
__global__ __launch_bounds__(256) void k_stats(const float* __restrict__ u, float* __restrict__ sums) {
    __shared__ float s1[256], s2[256];
    int tid = threadIdx.x;
    float a = 0.f, b = 0.f;
    for (size_t i = (size_t)blockIdx.x * 256 + tid; i < (size_t)N_NODES * 64; i += (size_t)gridDim.x * 256) {
        float v = u[i];
        a += v;
        b += v * v;
    }
    s1[tid] = a; s2[tid] = b;
    __syncthreads();
    if (tid < 128) { s1[tid] += s1[tid + 128]; s2[tid] += s2[tid + 128]; }
    __syncthreads();
    if (tid < 64) {
        atomicAdd(&sums[tid], s1[tid] + s1[tid + 64]);
        atomicAdd(&sums[64 + tid], s2[tid] + s2[tid + 64]);
    }
}

__global__ __launch_bounds__(64) void k_finalize(const float* __restrict__ sums,
                                                 const float* __restrict__ g,
                                                 const float* __restrict__ be,
                                                 float* __restrict__ scsh, float inv_n) {
    int c = threadIdx.x;
    float mean = sums[c] * inv_n;
    float var = sums[64 + c] * inv_n - mean * mean;
    if (var < 0.f) var = 0.f;
    float inv = rsqrtf(var + 1e-5f);
    float sc = inv * g[c];
    scsh[c] = sc;
    scsh[64 + c] = be[c] - mean * sc;
}

// ---------------- per-layer pooling (batch is sorted); 4 waves split the node range ----------------
__global__ __launch_bounds__(256) void k_pool1(const int* __restrict__ batch,
                                               const float* __restrict__ h,
                                               float* __restrict__ pooled, int layer) {
    __shared__ float red[256];
    int g = blockIdx.x, tid = threadIdx.x;
    int c = tid & 63, wv = tid >> 6;
    int lo = 0, hi = N_NODES;
    while (lo < hi) { int mid = (lo + hi) >> 1; if (batch[mid] < g) lo = mid + 1; else hi = mid; }
    int s = lo;
    lo = s; hi = N_NODES;
    while (lo < hi) { int mid = (lo + hi) >> 1; if (batch[mid] < g + 1) lo = mid + 1; else hi = mid; }
    int e = lo;
    int len = e - s;
    int chunk = (len + 3) >> 2;
    int ns = s + wv * chunk;
    int ne = ns + chunk; if (ne > e) ne = e;
    float a0 = 0.f, a1 = 0.f, a2 = 0.f, a3 = 0.f, a4 = 0.f, a5 = 0.f, a6 = 0.f, a7 = 0.f;
    int n = ns;
    for (; n + 8 <= ne; n += 8) {
        a0 += h[(size_t)(n + 0) * 64 + c];
        a1 += h[(size_t)(n + 1) * 64 + c];
        a2 += h[(size_t)(n + 2) * 64 + c];
        a3 += h[(size_t)(n + 3) * 64 + c];
        a4 += h[(size_t)(n + 4) * 64 + c];
        a5 += h[(size_t)(n + 5) * 64 + c];
        a6 += h[(size_t)(n + 6) * 64 + c];
        a7 += h[(size_t)(n + 7) * 64 + c];
    }
    for (; n < ne; ++n) a0 += h[(size_t)n * 64 + c];
    red[tid] = ((a0 + a1) + (a2 + a3)) + ((a4 + a5) + (a6 + a7));
    __syncthreads();
    if (wv == 0)
        pooled[g * 256 + layer * 64 + c] = (red[c] + red[64 + c]) + (red[128 + c] + red[192 + c]);
}

// ---------------- head ----------------
__global__ __launch_bounds__(64) void k_head1(const float* __restrict__ pooled,
                                              const float* __restrict__ W, const float* __restrict__ b,
                                              float* __restrict__ t1) {
    int g = blockIdx.x, lane = threadIdx.x;
    const float* p = pooled + g * 256;
    float acc = b[lane];
    for (int k = 0; k < 256; ++k) acc += p[k] * W[k * 64 + lane];
    t1[g * 64 + lane] = acc;
}

__global__ __launch_bounds__(64) void k_head2(const float* __restrict__ t1,
                                              const float* __restrict__ g_, const float* __restrict__ b_,
                                              float* __restrict__ scsh) {
    int c = threadIdx.x;
    float s = 0.f, q = 0.f;
    for (int r = 0; r < N_GRAPHS; ++r) {
        float v = t1[r * 64 + c];
        s += v; q += v * v;
    }
    float mean = s * (1.0f / N_GRAPHS);
    float var = q * (1.0f / N_GRAPHS) - mean * mean;
    if (var < 0.f) var = 0.f;
    float inv = rsqrtf(var + 1e-5f);
    float sc = inv * g_[c];
    scsh[c] = sc;
    scsh[64 + c] = b_[c] - mean * sc;
}

__global__ __launch_bounds__(64) void k_head3(const float* __restrict__ t1, const float* __restrict__ scsh,
                                              const float* __restrict__ W2, const float* __restrict__ b2,
                                              float* __restrict__ out) {
    __shared__ float v[64];
    __shared__ float o[16];
    int g = blockIdx.x, lane = threadIdx.x;
    float x = t1[g * 64 + lane] * scsh[lane] + scsh[64 + lane];
    v[lane] = fmaxf(x, 0.f);
    __syncthreads();
    if (lane < N_CLASSES) {
        float acc = b2[lane];
        for (int k = 0; k < 64; ++k) acc += v[k] * W2[k * N_CLASSES + lane];
        o[lane] = acc;
    }
    __syncthreads();
    if (lane < N_CLASSES) {
        float m = -1e30f;
        for (int k = 0; k < N_CLASSES; ++k) m = fmaxf(m, o[k]);
        float ssum = 0.f;
        for (int k = 0; k < N_CLASSES; ++k) ssum += expf(o[k] - m);
        out[g * N_CLASSES + lane] = o[lane] - m - logf(ssum);
    }
}

// ---------------- launch ----------------
extern "C" void kernel_launch(void* const* d_in, const int* in_sizes, int n_in,
                              void* d_out, int out_size, void* d_ws, size_t ws_size,
                              hipStream_t stream) {
    const float* x      = (const float*)d_in[0];
    const int*   ei     = (const int*)d_in[1];
    const int*   srcArr = ei;
    const int*   dstArr = ei + N_EDGES;
    const int*   batch  = (const int*)d_in[2];
    const float* eps    = (const float*)d_in[3];
    const float* W1_0   = (const float*)d_in[4];
    const float* b1_0   = (const float*)d_in[5];
    const float* g_0    = (const float*)d_in[6];
    const float* be_0   = (const float*)d_in[7];
    const float* W2_0   = (const float*)d_in[8];
    const float* b2_0   = (const float*)d_in[9];
    const float* W1_r   = (const float*)d_in[10];
    const float* b1_r   = (const float*)d_in[11];
    const float* g_r    = (const float*)d_in[12];
    const float* be_r   = (const float*)d_in[13];
    const float* W2_r   = (const float*)d_in[14];
    const float* b2_r   = (const float*)d_in[15];
    const float* lin1W  = (const float*)d_in[16];
    const float* lin1b  = (const float*)d_in[17];
    const float* bn_g   = (const float*)d_in[18];
    const float* bn_b   = (const float*)d_in[19];
    const float* lin2W  = (const float*)d_in[20];
    const float* lin2b  = (const float*)d_in[21];

    char* ws = (char*)d_ws;
    auto alloc = [&](size_t bytes) {
        char* p = ws;
        ws += (bytes + 255) & ~(size_t)255;
        return p;
    };
    int*   deg     = (int*)alloc((size_t)N_NODES * 4);
    int*   row_ptr = (int*)alloc(((size_t)N_NODES + 1) * 4);
    int*   cursor  = (int*)alloc(((size_t)N_NODES + 1) * 4);
    int*   bsum    = (int*)alloc((size_t)N_TILES * 4);
    int*   boff    = (int*)alloc(((size_t)N_TILES + 1) * 4);
    int*   col_src = (int*)alloc((size_t)N_EDGES * 4);
    float* ybuf    = (float*)alloc((size_t)N_NODES * 64 * 4);
    float* u       = (float*)alloc((size_t)N_NODES * 64 * 4);
    float* hA      = (float*)alloc((size_t)N_NODES * 64 * 4);
    float* hB      = (float*)alloc((size_t)N_NODES * 64 * 4);
    float* statsA  = (float*)alloc(NLAYERS * 128 * 4);
    float* scsh    = (float*)alloc(NLAYERS * 128 * 4);
    float* pooled  = (float*)alloc((size_t)N_GRAPHS * 256 * 4);
    float* t1      = (float*)alloc((size_t)N_GRAPHS * 64 * 4);
    float* hscsh   = (float*)alloc(128 * 4);

    hipMemsetAsync(deg, 0, (size_t)N_NODES * 4, stream);
    hipMemsetAsync(statsA, 0, NLAYERS * 128 * 4, stream);

    const int e4_grid = (N_EDGES + 1023) / 1024;
    k_degree<<<e4_grid, 256, 0, stream>>>(dstArr, deg);
    k_tilesum<<<N_TILES, 256, 0, stream>>>(deg, bsum);
    k_tilescan<<<1, 512, 0, stream>>>(bsum, boff);
    k_tileapply<<<N_TILES, 256, 0, stream>>>(deg, boff, row_ptr);
    hipMemcpyAsync(cursor, row_ptr, (size_t)N_NODES * 4, hipMemcpyDeviceToDevice, stream);
    k_fill<<<e4_grid, 256, 0, stream>>>(srcArr, dstArr, cursor, col_src);

    const int agg_grid  = N_NODES / 4;            // 25000, exact
    const int gemm_grid = N_NODES / 16;           // 6250, exact

    const float* hin = x;
    float* hping[2] = {hA, hB};
    for (int l = 0; l < NLAYERS; ++l) {
        const float *W1, *b1, *gg, *be, *W2, *b2;
        if (l == 0) { W1 = W1_0; b1 = b1_0; gg = g_0; be = be_0; W2 = W2_0; b2 = b2_0; }
        else {
            W1 = W1_r + (size_t)(l - 1) * 64 * 64;
            b1 = b1_r + (size_t)(l - 1) * 64;
            gg = g_r  + (size_t)(l - 1) * 64;
            be = be_r + (size_t)(l - 1) * 64;
            W2 = W2_r + (size_t)(l - 1) * 64 * 64;
            b2 = b2_r + (size_t)(l - 1) * 64;
        }
        float* hout = hping[l & 1];
        // y = h @ W1  (bias folded into aggregate)
        if (l == 0) k_gemm_f32<128><<<gemm_grid, 256, 0, stream>>>(hin, W1, ybuf);
        else        k_gemm_f32<64><<<gemm_grid, 256, 0, stream>>>(hin, W1, ybuf);
        // u = (1+eps)*y + sum y[src] + b1
        k_aggregate_u<<<agg_grid, 256, 0, stream>>>(ybuf, row_ptr, col_src, eps, l, b1, u);
        k_stats<<<256, 256, 0, stream>>>(u, statsA + l * 128);
        k_finalize<<<1, 64, 0, stream>>>(statsA + l * 128, gg, be, scsh + l * 128, 1.0f / N_NODES);
        // h = relu( relu(bn(u)) @ W2 + b2 )
        k_gemm_bn<<<gemm_grid, 256, 0, stream>>>(u, W2, scsh + l * 128, b2, hout);
        k_pool1<<<N_GRAPHS, 256, 0, stream>>>(batch, hout, pooled, l);
        hin = hout;
    }

    k_head1<<<N_GRAPHS, 64, 0, stream>>>(pooled, lin1W, lin1b, t1);
    k_head2<<<1, 64, 0, stream>>>(t1, bn_g, bn_b, hscsh);
    k_head3<<<N_GRAPHS, 64, 0, stream>>>(t1, hscsh, lin2W, lin2b, (float*)d_out);
}